// Round 8
// baseline (1680.029 us; speedup 1.0000x reference)
//
#include <hip/hip_runtime.h>
#include <hip/hip_bf16.h>
#include <hip/hip_fp16.h>
#include <math.h>

// ---------------- problem constants ----------------
#define BB 64
#define CC 1024
#define NH 32
#define NTOK (BB * 14 * 14)      // 12544
#define SCALE 0.17677669529663687f  // 32^-0.5

typedef __attribute__((ext_vector_type(8))) short short8;
typedef __attribute__((ext_vector_type(8))) unsigned short us8;
typedef __attribute__((ext_vector_type(4))) float f32x4;

// ---------------- static device workspace ----------------
__device__ __align__(16) float  g_X  [(size_t)NTOK * CC];        // residual (fp32)
__device__ __align__(16) float  g_QKV[(size_t)NTOK * 3072];      // qkv out (fp32)
__device__ __align__(16) unsigned short g_B[(size_t)NTOK * CC];   // fp16 acts (1024-wide)
__device__ __align__(16) unsigned short g_C[(size_t)NTOK * 4096]; // fp16 fc1 out
// transposed fp16 weights [N][K], 2 blocks each
__device__ __align__(16) unsigned short g_Wq[(size_t)2*3072*1024];
__device__ __align__(16) unsigned short g_Wp[(size_t)2*1024*1024];
__device__ __align__(16) unsigned short g_W1[(size_t)2*4096*1024];
__device__ __align__(16) unsigned short g_W2[(size_t)2*1024*4096];
__device__ __align__(16) float g_H0[64 * CC];
__device__ __align__(16) float g_H1[64 * 512];
__device__ __align__(16) float g_H2[64 * 128];

__device__ __forceinline__ float gelu_f(float x) {
    return 0.5f * x * (1.0f + erff(x * 0.70710678118654752f));
}

__device__ __forceinline__ unsigned short f16_bits(float v) {
    _Float16 hh = (_Float16)v;
    return *(unsigned short*)&hh;
}

// window-order row r (bn*49+t) -> row in X ([B,14,14] flattened)
__device__ __forceinline__ int win_to_xrow(int r, int shifted) {
    int bn = r / 49, t = r - bn * 49;
    int b = bn >> 2, w = bn & 3;
    int wh = w >> 1, ww_ = w & 1;
    int th = t / 7, tw = t - th * 7;
    int gh = wh * 7 + th, gw = ww_ * 7 + tw;
    if (shifted) { gh = gh + 3; if (gh >= 14) gh -= 14; gw = gw + 3; if (gw >= 14) gw -= 14; }
    return b * 196 + gh * 14 + gw;
}

__device__ __forceinline__ void gload_lds16(const void* g, void* l) {
    __builtin_amdgcn_global_load_lds(
        (const __attribute__((address_space(1))) unsigned int*)g,
        (__attribute__((address_space(3))) unsigned int*)l, 16, 0, 0);
}

// ---------------- weight convert + transpose: W[K][N] fp32 -> WT[N][K] fp16 --
__global__ __launch_bounds__(256) void convw_kernel(const float* __restrict__ W,
    unsigned short* __restrict__ Wh, int K, int N)
{
    __shared__ float t[32][33];
    int n0 = blockIdx.x * 32, k0 = blockIdx.y * 32;
    int tx = threadIdx.x & 31, ty = threadIdx.x >> 5;
    #pragma unroll
    for (int i = 0; i < 4; ++i)
        t[ty + 8 * i][tx] = W[(size_t)(k0 + ty + 8 * i) * N + n0 + tx];
    __syncthreads();
    #pragma unroll
    for (int i = 0; i < 4; ++i) {
        int n = ty + 8 * i;
        Wh[(size_t)(n0 + n) * K + k0 + tx] = f16_bits(t[tx][n]);
    }
}

// ---------------- LayerNorm -> fp16 (optional window partition+shift) --------
__global__ __launch_bounds__(256) void ln_kernel(const float* __restrict__ X,
    const float* __restrict__ g, const float* __restrict__ bta,
    unsigned short* __restrict__ outh, int shifted, int partition)
{
    int token = blockIdx.x * 4 + (threadIdx.x >> 6);
    int lane = threadIdx.x & 63;
    int xrow = partition ? win_to_xrow(token, shifted) : token;
    const float4* src = (const float4*)(X + (size_t)xrow * CC);
    float4 v[4];
    float s = 0.f;
    #pragma unroll
    for (int w = 0; w < 4; ++w) {
        v[w] = src[w * 64 + lane];
        s += v[w].x + v[w].y + v[w].z + v[w].w;
    }
    #pragma unroll
    for (int o = 32; o; o >>= 1) s += __shfl_xor(s, o);
    float mean = s * (1.0f / CC);
    float ss = 0.f;
    #pragma unroll
    for (int w = 0; w < 4; ++w) {
        float d0 = v[w].x - mean, d1 = v[w].y - mean, d2 = v[w].z - mean, d3 = v[w].w - mean;
        ss += d0 * d0 + d1 * d1 + d2 * d2 + d3 * d3;
    }
    #pragma unroll
    for (int o = 32; o; o >>= 1) ss += __shfl_xor(ss, o);
    float inv = 1.0f / sqrtf(ss * (1.0f / CC) + 1e-5f);
    #pragma unroll
    for (int w = 0; w < 4; ++w) {
        int c4 = w * 64 + lane;
        float4 gv = *(const float4*)(g + c4 * 4);
        float4 bv = *(const float4*)(bta + c4 * 4);
        ushort4 uo;
        uo.x = f16_bits((v[w].x - mean) * inv * gv.x + bv.x);
        uo.y = f16_bits((v[w].y - mean) * inv * gv.y + bv.y);
        uo.z = f16_bits((v[w].z - mean) * inv * gv.z + bv.z);
        uo.w = f16_bits((v[w].w - mean) * inv * gv.w + bv.w);
        *(ushort4*)(outh + (size_t)token * CC + c4 * 4) = uo;
    }
}

// ---------------- fp16 MFMA GEMM: C = A[M][K] * W[N][K]^T --------------------
// 128x128 tile, BK=64, 4 waves (2x2), 4x4 16x16x32 frags/wave.
// Double-buffered LDS (2 x 32KB), 2-phase prefetch: STAGE(t+1) issued before
// compute(t); one counted vmcnt(0) + raw s_barrier per K-tile (T3+T4 minimum).
// XOR swizzle slot^=row&7 on both global source and ds_read side.
// EPI: 0 fp32 store+bias (QKV); 1 gelu -> fp16 store, LDS-coalesced (FC1);
//      2 residual += into X via window map (proj); 3 residual += direct (FC2)
template<int EPI>
__global__ __launch_bounds__(256, 2) void gemm_mfma(
    const unsigned short* __restrict__ A, const unsigned short* __restrict__ W,
    const float* __restrict__ bias,
    float* __restrict__ outf, unsigned short* __restrict__ outh,
    int N, int K, int shifted, int NR, int GC)
{
    __shared__ unsigned short sm[32768];   // 2 bufs x (2 tiles x [128][64] fp16)
    const int tid = threadIdx.x;
    const int wave = tid >> 6, lane = tid & 63;
    const int wr = wave >> 1, wc = wave & 1;
    // ---- grid remap: XCD chunk + col-group supertile
    const int nb = gridDim.x;
    const int wg = (blockIdx.x & 7) * (nb >> 3) + (blockIdx.x >> 3);
    const int gsz = GC * NR;
    const int grp = wg / gsz;
    const int rem = wg - grp * gsz;
    const int by = rem / GC;
    const int bx = grp * GC + (rem - by * GC);
    const int row0 = by * 128, col0 = bx * 128;
    const int rsel = lane & 15;

    f32x4 acc[4][4] = {};

    const int srow = tid >> 3, sslot = tid & 7;

    auto STAGE = [&](int bufSel, int k0) {
        #pragma unroll
        for (int i = 0; i < 8; ++i) {
            const int t = i >> 2;               // tile id 0..1 (compile-time)
            const int sub = i & 3;              // 32-row group
            const int row = sub * 32 + srow;
            const int c = sslot ^ (row & 7);    // global k-chunk for this slot
            const unsigned short* gp = (t == 0) ? A : W;
            const int rb = (t == 0) ? row0 : col0;
            gload_lds16(gp + (size_t)(rb + row) * K + k0 + c * 8,
                        &sm[bufSel * 16384 + t * 8192 + sub * 2048 + tid * 8]);
        }
    };

    const int nt = K >> 6;
    int cur = 0;
    // prologue: stage tile 0, drain, sync
    STAGE(0, 0);
    asm volatile("s_waitcnt vmcnt(0)" ::: "memory");
    __builtin_amdgcn_sched_barrier(0);
    __builtin_amdgcn_s_barrier();

    for (int t = 0; t < nt; ++t) {
        if (t + 1 < nt) STAGE(cur ^ 1, (t + 1) << 6);   // prefetch next tile
        const int bb = cur * 16384;
        // ---- compute current tile: per 32-K step, 8 ds_read_b128 + 16 MFMA
        #pragma unroll
        for (int kk = 0; kk < 2; ++kk) {
            const int kc8 = kk * 4 + (lane >> 4);
            short8 fa[4], fw[4];
            #pragma unroll
            for (int m = 0; m < 4; ++m) {
                int ra = wr * 64 + m * 16 + rsel;
                fa[m] = *(const short8*)&sm[bb + ra * 64 + ((kc8 ^ (ra & 7)) * 8)];
                int rw = wc * 64 + m * 16 + rsel;
                fw[m] = *(const short8*)&sm[bb + 8192 + rw * 64 + ((kc8 ^ (rw & 7)) * 8)];
            }
            #pragma unroll
            for (int m = 0; m < 4; ++m)
                #pragma unroll
                for (int n = 0; n < 4; ++n)
                    acc[m][n] = __builtin_amdgcn_mfma_f32_16x16x32_f16(fa[m], fw[n], acc[m][n], 0, 0, 0);
        }
        // prefetch landed + everyone done reading cur before it's overwritten
        asm volatile("s_waitcnt vmcnt(0)" ::: "memory");
        __builtin_amdgcn_sched_barrier(0);
        __builtin_amdgcn_s_barrier();
        cur ^= 1;
    }

    // ---- epilogue: D layout col=lane&15, row=(lane>>4)*4+j
    const int jrow = lane >> 4;
    if (EPI == 0) {
        #pragma unroll
        for (int n = 0; n < 4; ++n) {
            int c = col0 + wc * 64 + n * 16 + rsel;
            float bv = bias[c];
            #pragma unroll
            for (int m = 0; m < 4; ++m)
                #pragma unroll
                for (int j = 0; j < 4; ++j) {
                    int r = row0 + wr * 64 + m * 16 + jrow * 4 + j;
                    outf[(size_t)r * N + c] = acc[m][n][j] + bv;
                }
        }
    } else if (EPI == 1) {
        // write tile into LDS (stride 132: conflict-free), then stream coalesced
        #pragma unroll
        for (int n = 0; n < 4; ++n) {
            int cl = wc * 64 + n * 16 + rsel;
            float bv = bias[col0 + cl];
            #pragma unroll
            for (int m = 0; m < 4; ++m)
                #pragma unroll
                for (int j = 0; j < 4; ++j) {
                    int rl = wr * 64 + m * 16 + jrow * 4 + j;
                    sm[rl * 132 + cl] = f16_bits(gelu_f(acc[m][n][j] + bv));
                }
        }
        __syncthreads();
        const int r = tid >> 1, cb = (tid & 1) * 64;
        unsigned short* dst = outh + (size_t)(row0 + r) * N + col0 + cb;
        const unsigned short* src = &sm[r * 132 + cb];
        #pragma unroll
        for (int i = 0; i < 8; ++i)
            *(us8*)(dst + i * 8) = *(const us8*)(src + i * 8);
    } else {
        // EPI 2/3: residual add, LDS restage -> full-line float4 RMW
        float* smf = (float*)sm;
        const int rr = tid >> 2;             // local row 0..63
        const int cc4 = (tid & 3) * 32;      // col offset 0/32/64/96
        #pragma unroll
        for (int half = 0; half < 2; ++half) {
            __syncthreads();
            if (wr == half) {
                #pragma unroll
                for (int n = 0; n < 4; ++n) {
                    const int cl = wc * 64 + n * 16 + rsel;
                    const float bv = bias[col0 + cl];
                    #pragma unroll
                    for (int m = 0; m < 4; ++m)
                        #pragma unroll
                        for (int j = 0; j < 4; ++j)
                            smf[(m * 16 + jrow * 4 + j) * 130 + cl] = acc[m][n][j] + bv;
                }
            }
            __syncthreads();
            const int gr = row0 + half * 64 + rr;
            const int orow = (EPI == 2) ? win_to_xrow(gr, shifted) : gr;
            float* dst = outf + (size_t)orow * CC + col0 + cc4;
            const float* srcl = &smf[rr * 130 + cc4];
            #pragma unroll
            for (int i = 0; i < 8; ++i) {
                float4 xv = *(float4*)(dst + i * 4);
                xv.x += srcl[i * 4 + 0];
                xv.y += srcl[i * 4 + 1];
                xv.z += srcl[i * 4 + 2];
                xv.w += srcl[i * 4 + 3];
                *(float4*)(dst + i * 4) = xv;
            }
        }
    }
}

// ---------------- windowed attention: 4 waves/block, one head per wave -------
// grid = 256 windows * 8 head-groups; scores in registers, K/V fp32 in LDS
__global__ __launch_bounds__(256) void attn_kernel(const float* __restrict__ qkv,
    unsigned short* __restrict__ oh, const float* __restrict__ rpb, int shifted)
{
    int blk = blockIdx.x;
    int bn = blk >> 3;                 // window 0..255
    int hg = blk & 7;                  // head group 0..7
    int wv = threadIdx.x >> 6;
    int lane = threadIdx.x & 63;
    int h = hg * 4 + wv;

    __shared__ float ks[4][49][32], vs[4][49][32];   // 49KB

    // each wave loads its own head's K,V (coalesced 128B chunks)
    for (int idx = lane; idx < 49 * 32; idx += 64) {
        int t = idx >> 5, d = idx & 31;
        const float* p = qkv + (size_t)(bn * 49 + t) * 3072 + h * 32 + d;
        ks[wv][t][d] = p[1024];
        vs[wv][t][d] = p[2048];
    }
    __syncthreads();

    if (lane < 49) {
        const int i = lane;
        const int ih = i / 7, iw = i - ih * 7;
        const int w = bn & 3, wh = w >> 1, ww_ = w & 1;
        const int gh = wh * 7 + ih, gw = ww_ * 7 + iw;
        const int li = (gh < 7 ? 0 : (gh < 11 ? 1 : 2)) * 3 + (gw < 7 ? 0 : (gw < 11 ? 1 : 2));

        // Q row straight to registers
        float qreg[32];
        const float* qp = qkv + (size_t)(bn * 49 + i) * 3072 + h * 32;
        #pragma unroll
        for (int d4 = 0; d4 < 8; ++d4) {
            float4 qv = *(const float4*)(qp + d4 * 4);
            qreg[d4 * 4 + 0] = qv.x * SCALE;
            qreg[d4 * 4 + 1] = qv.y * SCALE;
            qreg[d4 * 4 + 2] = qv.z * SCALE;
            qreg[d4 * 4 + 3] = qv.w * SCALE;
        }

        float p[49];
        float mx = -1e30f;
        #pragma unroll
        for (int j = 0; j < 49; ++j) {
            const int jh = j / 7, jw = j - jh * 7;
            float dot = 0.f;
            #pragma unroll
            for (int d = 0; d < 32; ++d) dot = fmaf(qreg[d], ks[wv][j][d], dot);
            const int ridx = (ih - jh + 6) * 13 + (iw - jw + 6);
            float val = dot + rpb[ridx * 32 + h];
            if (shifted) {
                const int gjh = wh * 7 + jh, gjw = ww_ * 7 + jw;
                const int lj = (gjh < 7 ? 0 : (gjh < 11 ? 1 : 2)) * 3 +
                               (gjw < 7 ? 0 : (gjw < 11 ? 1 : 2));
                if (li != lj) val -= 100.0f;
            }
            p[j] = val;
            mx = fmaxf(mx, val);
        }
        float denom = 0.f;
        #pragma unroll
        for (int j = 0; j < 49; ++j) {
            p[j] = expf(p[j] - mx);
            denom += p[j];
        }
        const float rd = 1.0f / denom;

        unsigned short* orow = oh + (size_t)(bn * 49 + i) * CC + h * 32;
        #pragma unroll 4
        for (int d = 0; d < 32; ++d) {
            float acc = 0.f;
            #pragma unroll
            for (int j = 0; j < 49; ++j) acc = fmaf(p[j], vs[wv][j][d], acc);
            orow[d] = f16_bits(acc * rd);
        }
    }
}

// ---------------- global-avg-pool + LayerNorm --------------------------------
__global__ __launch_bounds__(256) void pool_ln_kernel(const float* __restrict__ X,
    const float* __restrict__ g, const float* __restrict__ bta, float* __restrict__ out)
{
    int b = blockIdx.x, tid = threadIdx.x;
    int lane = tid & 63, wid = tid >> 6;
    const float* base = X + (size_t)b * 196 * CC + tid * 4;
    float a0 = 0, a1 = 0, a2 = 0, a3 = 0;
    for (int t = 0; t < 196; ++t) {
        float4 v = *(const float4*)(base + (size_t)t * CC);
        a0 += v.x; a1 += v.y; a2 += v.z; a3 += v.w;
    }
    const float inv196 = 1.0f / 196.0f;
    float p0 = a0 * inv196, p1 = a1 * inv196, p2 = a2 * inv196, p3 = a3 * inv196;
    float s = p0 + p1 + p2 + p3;
    #pragma unroll
    for (int o = 32; o; o >>= 1) s += __shfl_xor(s, o);
    __shared__ float sred[4], ssred[4];
    if (lane == 0) sred[wid] = s;
    __syncthreads();
    float mean = (sred[0] + sred[1] + sred[2] + sred[3]) * (1.0f / CC);
    float d0 = p0 - mean, d1 = p1 - mean, d2 = p2 - mean, d3 = p3 - mean;
    float ss = d0 * d0 + d1 * d1 + d2 * d2 + d3 * d3;
    #pragma unroll
    for (int o = 32; o; o >>= 1) ss += __shfl_xor(ss, o);
    if (lane == 0) ssred[wid] = ss;
    __syncthreads();
    float var = (ssred[0] + ssred[1] + ssred[2] + ssred[3]) * (1.0f / CC);
    float inv = 1.0f / sqrtf(var + 1e-5f);
    float4 gv = *(const float4*)(g + tid * 4);
    float4 bv = *(const float4*)(bta + tid * 4);
    float4 o4;
    o4.x = d0 * inv * gv.x + bv.x;
    o4.y = d1 * inv * gv.y + bv.y;
    o4.z = d2 * inv * gv.z + bv.z;
    o4.w = d3 * inv * gv.w + bv.w;
    *(float4*)(out + (size_t)b * CC + tid * 4) = o4;
}

// ---------------- head GEMM: one block per row, A row in LDS -----------------
__global__ __launch_bounds__(256) void head_rowgemm(const float* __restrict__ A,
    const float* __restrict__ W, const float* __restrict__ bias,
    float* __restrict__ out, int K, int N, int act)
{
    __shared__ float As[1024];
    int r = blockIdx.x, tid = threadIdx.x;
    for (int k = tid; k < K; k += 256) As[k] = A[(size_t)r * K + k];
    __syncthreads();
    for (int c = tid; c < N; c += 256) {
        float s0 = 0.f, s1 = 0.f;
        for (int k = 0; k < K; k += 2) {
            s0 = fmaf(As[k],     W[(size_t)k * N + c],       s0);
            s1 = fmaf(As[k + 1], W[(size_t)(k + 1) * N + c], s1);
        }
        float s = s0 + s1 + bias[c];
        out[(size_t)r * N + c] = act ? gelu_f(s) : s;
    }
}

// ---------------- launch ------------------------------------------------------
extern "C" void kernel_launch(void* const* d_in, const int* in_sizes, int n_in,
                              void* d_out, int out_size, void* d_ws, size_t ws_size,
                              hipStream_t stream) {
    const float* x = (const float*)d_in[0];
    auto P = [&](int i) { return (const float*)d_in[i]; };

    float *X, *QKV, *H0, *H1, *H2;
    unsigned short *B, *C, *Wq, *Wp, *W1, *W2;
    { void* p;
      hipGetSymbolAddress(&p, HIP_SYMBOL(g_X));   X   = (float*)p;
      hipGetSymbolAddress(&p, HIP_SYMBOL(g_QKV)); QKV = (float*)p;
      hipGetSymbolAddress(&p, HIP_SYMBOL(g_B));   B   = (unsigned short*)p;
      hipGetSymbolAddress(&p, HIP_SYMBOL(g_C));   C   = (unsigned short*)p;
      hipGetSymbolAddress(&p, HIP_SYMBOL(g_Wq));  Wq  = (unsigned short*)p;
      hipGetSymbolAddress(&p, HIP_SYMBOL(g_Wp));  Wp  = (unsigned short*)p;
      hipGetSymbolAddress(&p, HIP_SYMBOL(g_W1));  W1  = (unsigned short*)p;
      hipGetSymbolAddress(&p, HIP_SYMBOL(g_W2));  W2  = (unsigned short*)p;
      hipGetSymbolAddress(&p, HIP_SYMBOL(g_H0));  H0 = (float*)p;
      hipGetSymbolAddress(&p, HIP_SYMBOL(g_H1));  H1 = (float*)p;
      hipGetSymbolAddress(&p, HIP_SYMBOL(g_H2));  H2 = (float*)p;
    }

    hipMemcpyAsync(X, x, (size_t)NTOK * CC * sizeof(float),
                   hipMemcpyDeviceToDevice, stream);

    // weight conversion + transpose (per launch; weights are inputs)
    for (int blk = 0; blk < 2; ++blk) {
        int base = 1 + blk * 13;
        convw_kernel<<<dim3(3072/32, 1024/32), 256, 0, stream>>>(
            P(base + 2), Wq + (size_t)blk*3072*1024, 1024, 3072);
        convw_kernel<<<dim3(1024/32, 1024/32), 256, 0, stream>>>(
            P(base + 5), Wp + (size_t)blk*1024*1024, 1024, 1024);
        convw_kernel<<<dim3(4096/32, 1024/32), 256, 0, stream>>>(
            P(base + 9), W1 + (size_t)blk*4096*1024, 1024, 4096);
        convw_kernel<<<dim3(1024/32, 4096/32), 256, 0, stream>>>(
            P(base + 11), W2 + (size_t)blk*1024*4096, 4096, 1024);
    }

    for (int blk = 0; blk < 2; ++blk) {
        int base = 1 + blk * 13;
        const float *ln1g = P(base + 0), *ln1b = P(base + 1);
        const float *qkvb = P(base + 3);
        const float *rpb  = P(base + 4);
        const float *projb = P(base + 6);
        const float *ln2g = P(base + 7), *ln2b = P(base + 8);
        const float *fc1b = P(base + 10);
        const float *fc2b = P(base + 12);
        int shifted = blk;
        const unsigned short* wq = Wq + (size_t)blk*3072*1024;
        const unsigned short* wp = Wp + (size_t)blk*1024*1024;
        const unsigned short* w1 = W1 + (size_t)blk*4096*1024;
        const unsigned short* w2 = W2 + (size_t)blk*1024*4096;

        // LN1 + window partition (+shift): X -> B (fp16, window order)
        ln_kernel<<<NTOK / 4, 256, 0, stream>>>(X, ln1g, ln1b, B, shifted, 1);
        // QKV: [12544,1024] x [3072,1024]^T -> QKV fp32   (grid 2352, GC=8)
        gemm_mfma<0><<<2352, 256, 0, stream>>>(
            B, wq, qkvb, QKV, nullptr, 3072, 1024, 0, 98, 8);
        // attention -> B (fp16, window order); 4 heads/block
        attn_kernel<<<256 * 8, 256, 0, stream>>>(QKV, B, rpb, shifted);
        // proj + window-reverse (+unshift) + residual into X (grid 784, GC=8)
        gemm_mfma<2><<<784, 256, 0, stream>>>(
            B, wp, projb, X, nullptr, 1024, 1024, shifted, 98, 8);
        // LN2: X -> B
        ln_kernel<<<NTOK / 4, 256, 0, stream>>>(X, ln2g, ln2b, B, 0, 0);
        // FC1 + gelu -> C (fp16)  (grid 3136, GC=8)
        gemm_mfma<1><<<3136, 256, 0, stream>>>(
            B, w1, fc1b, nullptr, C, 4096, 1024, 0, 98, 8);
        // FC2 + residual into X   (grid 784, GC=8: A read once)
        gemm_mfma<3><<<784, 256, 0, stream>>>(
            C, w2, fc2b, X, nullptr, 1024, 4096, 0, 98, 8);
    }

    // head
    pool_ln_kernel<<<64, 256, 0, stream>>>(X, P(27), P(28), H0);
    head_rowgemm<<<64, 256, 0, stream>>>(H0, P(29), P(30), H1, 1024, 512, 1);
    head_rowgemm<<<64, 256, 0, stream>>>(H1, P(31), P(32), H2, 512, 128, 1);
    head_rowgemm<<<64, 256, 0, stream>>>(H2, P(33), P(34), (float*)d_out, 128, 2, 0);
}

// Round 9
// 1597.616 us; speedup vs baseline: 1.0516x; 1.0516x over previous
//
#include <hip/hip_runtime.h>
#include <hip/hip_bf16.h>
#include <hip/hip_fp16.h>
#include <math.h>

// ---------------- problem constants ----------------
#define BB 64
#define CC 1024
#define NH 32
#define NTOK (BB * 14 * 14)      // 12544
#define SCALE 0.17677669529663687f  // 32^-0.5

typedef __attribute__((ext_vector_type(8))) short short8;
typedef __attribute__((ext_vector_type(8))) unsigned short us8;
typedef __attribute__((ext_vector_type(4))) float f32x4;

// ---------------- static device workspace ----------------
__device__ __align__(16) float  g_X  [(size_t)NTOK * CC];        // residual (fp32)
__device__ __align__(16) float  g_QKV[(size_t)NTOK * 3072];      // qkv out (fp32)
__device__ __align__(16) unsigned short g_B[(size_t)NTOK * CC];   // fp16 acts (1024-wide)
__device__ __align__(16) unsigned short g_C[(size_t)NTOK * 4096]; // fp16 fc1 out
// transposed fp16 weights [N][K], 2 blocks each
__device__ __align__(16) unsigned short g_Wq[(size_t)2*3072*1024];
__device__ __align__(16) unsigned short g_Wp[(size_t)2*1024*1024];
__device__ __align__(16) unsigned short g_W1[(size_t)2*4096*1024];
__device__ __align__(16) unsigned short g_W2[(size_t)2*1024*4096];
__device__ __align__(16) float g_H0[64 * CC];
__device__ __align__(16) float g_H1[64 * 512];
__device__ __align__(16) float g_H2[64 * 128];

__device__ __forceinline__ float gelu_f(float x) {
    return 0.5f * x * (1.0f + erff(x * 0.70710678118654752f));
}

__device__ __forceinline__ unsigned short f16_bits(float v) {
    _Float16 hh = (_Float16)v;
    return *(unsigned short*)&hh;
}

// window-order row r (bn*49+t) -> row in X ([B,14,14] flattened)
__device__ __forceinline__ int win_to_xrow(int r, int shifted) {
    int bn = r / 49, t = r - bn * 49;
    int b = bn >> 2, w = bn & 3;
    int wh = w >> 1, ww_ = w & 1;
    int th = t / 7, tw = t - th * 7;
    int gh = wh * 7 + th, gw = ww_ * 7 + tw;
    if (shifted) { gh = gh + 3; if (gh >= 14) gh -= 14; gw = gw + 3; if (gw >= 14) gw -= 14; }
    return b * 196 + gh * 14 + gw;
}

__device__ __forceinline__ void gload_lds16(const void* g, void* l) {
    __builtin_amdgcn_global_load_lds(
        (const __attribute__((address_space(1))) unsigned int*)g,
        (__attribute__((address_space(3))) unsigned int*)l, 16, 0, 0);
}

// ---------------- weight convert + transpose: W[K][N] fp32 -> WT[N][K] fp16 --
__global__ __launch_bounds__(256) void convw_kernel(const float* __restrict__ W,
    unsigned short* __restrict__ Wh, int K, int N)
{
    __shared__ float t[32][33];
    int n0 = blockIdx.x * 32, k0 = blockIdx.y * 32;
    int tx = threadIdx.x & 31, ty = threadIdx.x >> 5;
    #pragma unroll
    for (int i = 0; i < 4; ++i)
        t[ty + 8 * i][tx] = W[(size_t)(k0 + ty + 8 * i) * N + n0 + tx];
    __syncthreads();
    #pragma unroll
    for (int i = 0; i < 4; ++i) {
        int n = ty + 8 * i;
        Wh[(size_t)(n0 + n) * K + k0 + tx] = f16_bits(t[tx][n]);
    }
}

// ---------------- LayerNorm -> fp16 (optional window partition+shift) --------
__global__ __launch_bounds__(256) void ln_kernel(const float* __restrict__ X,
    const float* __restrict__ g, const float* __restrict__ bta,
    unsigned short* __restrict__ outh, int shifted, int partition)
{
    int token = blockIdx.x * 4 + (threadIdx.x >> 6);
    int lane = threadIdx.x & 63;
    int xrow = partition ? win_to_xrow(token, shifted) : token;
    const float4* src = (const float4*)(X + (size_t)xrow * CC);
    float4 v[4];
    float s = 0.f;
    #pragma unroll
    for (int w = 0; w < 4; ++w) {
        v[w] = src[w * 64 + lane];
        s += v[w].x + v[w].y + v[w].z + v[w].w;
    }
    #pragma unroll
    for (int o = 32; o; o >>= 1) s += __shfl_xor(s, o);
    float mean = s * (1.0f / CC);
    float ss = 0.f;
    #pragma unroll
    for (int w = 0; w < 4; ++w) {
        float d0 = v[w].x - mean, d1 = v[w].y - mean, d2 = v[w].z - mean, d3 = v[w].w - mean;
        ss += d0 * d0 + d1 * d1 + d2 * d2 + d3 * d3;
    }
    #pragma unroll
    for (int o = 32; o; o >>= 1) ss += __shfl_xor(ss, o);
    float inv = 1.0f / sqrtf(ss * (1.0f / CC) + 1e-5f);
    #pragma unroll
    for (int w = 0; w < 4; ++w) {
        int c4 = w * 64 + lane;
        float4 gv = *(const float4*)(g + c4 * 4);
        float4 bv = *(const float4*)(bta + c4 * 4);
        ushort4 uo;
        uo.x = f16_bits((v[w].x - mean) * inv * gv.x + bv.x);
        uo.y = f16_bits((v[w].y - mean) * inv * gv.y + bv.y);
        uo.z = f16_bits((v[w].z - mean) * inv * gv.z + bv.z);
        uo.w = f16_bits((v[w].w - mean) * inv * gv.w + bv.w);
        *(ushort4*)(outh + (size_t)token * CC + c4 * 4) = uo;
    }
}

// ---------------- fp16 MFMA GEMM: C = A[M][K] * W[N][K]^T --------------------
// 128x128 tile, BK=64, 4 waves (2x2), 4x4 16x16x32 frags/wave, 32 MFMA/wave/K-tile.
// Single-buffered: 2 LDS tiles [128][64] fp16 = 32KB (proven round-6 structure;
// explicit double-buffer regressed via occupancy loss, round-8 post-mortem).
// XOR swizzle slot^=row&7 on both global source and ds_read side.
// EPI: 0 fp32 store+bias (QKV); 1 gelu -> fp16 store, LDS-coalesced (FC1);
//      2 residual += into X via window map (proj); 3 residual += direct (FC2)
//      (2/3 restage through LDS -> full-line float4 read-modify-write)
template<int EPI>
__global__ __launch_bounds__(256, 2) void gemm_mfma(
    const unsigned short* __restrict__ A, const unsigned short* __restrict__ W,
    const float* __restrict__ bias,
    float* __restrict__ outf, unsigned short* __restrict__ outh,
    int N, int K, int shifted, int NR, int GC)
{
    __shared__ unsigned short sm[EPI == 1 ? 16896 : (EPI >= 2 ? 16640 : 16384)];
    const int tid = threadIdx.x;
    const int wave = tid >> 6, lane = tid & 63;
    const int wr = wave >> 1, wc = wave & 1;
    // ---- grid remap: XCD chunk + col-group supertile
    const int nb = gridDim.x;
    const int wg = (blockIdx.x & 7) * (nb >> 3) + (blockIdx.x >> 3);
    const int gsz = GC * NR;
    const int grp = wg / gsz;
    const int rem = wg - grp * gsz;
    const int by = rem / GC;
    const int bx = grp * GC + (rem - by * GC);
    const int row0 = by * 128, col0 = bx * 128;
    const int rsel = lane & 15;

    f32x4 acc[4][4] = {};

    const int srow = tid >> 3, sslot = tid & 7;

    for (int k0 = 0; k0 < K; k0 += 64) {
        // ---- stage 2 tiles via global_load_lds (linear dest, swizzled source)
        #pragma unroll
        for (int i = 0; i < 8; ++i) {
            const int t = i >> 2;               // tile id 0..1 (compile-time)
            const int sub = i & 3;              // 32-row group
            const int row = sub * 32 + srow;
            const int c = sslot ^ (row & 7);    // global k-chunk for this slot
            const unsigned short* gp = (t == 0) ? A : W;
            const int rb = (t == 0) ? row0 : col0;
            gload_lds16(gp + (size_t)(rb + row) * K + k0 + c * 8,
                        &sm[t * 8192 + sub * 2048 + tid * 8]);
        }
        __syncthreads();

        // ---- per 32-K step: 8 ds_read_b128 + 16 MFMA
        #pragma unroll
        for (int kk = 0; kk < 2; ++kk) {
            const int kc8 = kk * 4 + (lane >> 4);
            short8 fa[4], fw[4];
            #pragma unroll
            for (int m = 0; m < 4; ++m) {
                int ra = wr * 64 + m * 16 + rsel;
                fa[m] = *(const short8*)&sm[ra * 64 + ((kc8 ^ (ra & 7)) * 8)];
                int rw = wc * 64 + m * 16 + rsel;
                fw[m] = *(const short8*)&sm[8192 + rw * 64 + ((kc8 ^ (rw & 7)) * 8)];
            }
            #pragma unroll
            for (int m = 0; m < 4; ++m)
                #pragma unroll
                for (int n = 0; n < 4; ++n)
                    acc[m][n] = __builtin_amdgcn_mfma_f32_16x16x32_f16(fa[m], fw[n], acc[m][n], 0, 0, 0);
        }
        __syncthreads();
    }

    // ---- epilogue: D layout col=lane&15, row=(lane>>4)*4+j
    const int jrow = lane >> 4;
    if (EPI == 0) {
        #pragma unroll
        for (int n = 0; n < 4; ++n) {
            int c = col0 + wc * 64 + n * 16 + rsel;
            float bv = bias[c];
            #pragma unroll
            for (int m = 0; m < 4; ++m)
                #pragma unroll
                for (int j = 0; j < 4; ++j) {
                    int r = row0 + wr * 64 + m * 16 + jrow * 4 + j;
                    outf[(size_t)r * N + c] = acc[m][n][j] + bv;
                }
        }
    } else if (EPI == 1) {
        // write tile into LDS (stride 132: conflict-free), then stream coalesced
        #pragma unroll
        for (int n = 0; n < 4; ++n) {
            int cl = wc * 64 + n * 16 + rsel;
            float bv = bias[col0 + cl];
            #pragma unroll
            for (int m = 0; m < 4; ++m)
                #pragma unroll
                for (int j = 0; j < 4; ++j) {
                    int rl = wr * 64 + m * 16 + jrow * 4 + j;
                    sm[rl * 132 + cl] = f16_bits(gelu_f(acc[m][n][j] + bv));
                }
        }
        __syncthreads();
        const int r = tid >> 1, cb = (tid & 1) * 64;
        unsigned short* dst = outh + (size_t)(row0 + r) * N + col0 + cb;
        const unsigned short* src = &sm[r * 132 + cb];
        #pragma unroll
        for (int i = 0; i < 8; ++i)
            *(us8*)(dst + i * 8) = *(const us8*)(src + i * 8);
    } else {
        // EPI 2/3: residual add, LDS restage -> full-line float4 RMW
        float* smf = (float*)sm;
        const int rr = tid >> 2;             // local row 0..63
        const int cc4 = (tid & 3) * 32;      // col offset 0/32/64/96
        #pragma unroll
        for (int half = 0; half < 2; ++half) {
            __syncthreads();
            if (wr == half) {
                #pragma unroll
                for (int n = 0; n < 4; ++n) {
                    const int cl = wc * 64 + n * 16 + rsel;
                    const float bv = bias[col0 + cl];
                    #pragma unroll
                    for (int m = 0; m < 4; ++m)
                        #pragma unroll
                        for (int j = 0; j < 4; ++j)
                            smf[(m * 16 + jrow * 4 + j) * 130 + cl] = acc[m][n][j] + bv;
                }
            }
            __syncthreads();
            const int gr = row0 + half * 64 + rr;
            const int orow = (EPI == 2) ? win_to_xrow(gr, shifted) : gr;
            float* dst = outf + (size_t)orow * CC + col0 + cc4;
            const float* srcl = &smf[rr * 130 + cc4];
            #pragma unroll
            for (int i = 0; i < 8; ++i) {
                float4 xv = *(float4*)(dst + i * 4);
                xv.x += srcl[i * 4 + 0];
                xv.y += srcl[i * 4 + 1];
                xv.z += srcl[i * 4 + 2];
                xv.w += srcl[i * 4 + 3];
                *(float4*)(dst + i * 4) = xv;
            }
        }
    }
}

// ---------------- windowed attention: 4 waves/block, one head per wave -------
// grid = 256 windows * 8 head-groups; scores in registers, K/V fp32 in LDS
__global__ __launch_bounds__(256) void attn_kernel(const float* __restrict__ qkv,
    unsigned short* __restrict__ oh, const float* __restrict__ rpb, int shifted)
{
    int blk = blockIdx.x;
    int bn = blk >> 3;                 // window 0..255
    int hg = blk & 7;                  // head group 0..7
    int wv = threadIdx.x >> 6;
    int lane = threadIdx.x & 63;
    int h = hg * 4 + wv;

    __shared__ float ks[4][49][32], vs[4][49][32];   // 49KB

    // each wave loads its own head's K,V (coalesced 128B chunks)
    for (int idx = lane; idx < 49 * 32; idx += 64) {
        int t = idx >> 5, d = idx & 31;
        const float* p = qkv + (size_t)(bn * 49 + t) * 3072 + h * 32 + d;
        ks[wv][t][d] = p[1024];
        vs[wv][t][d] = p[2048];
    }
    __syncthreads();

    if (lane < 49) {
        const int i = lane;
        const int ih = i / 7, iw = i - ih * 7;
        const int w = bn & 3, wh = w >> 1, ww_ = w & 1;
        const int gh = wh * 7 + ih, gw = ww_ * 7 + iw;
        const int li = (gh < 7 ? 0 : (gh < 11 ? 1 : 2)) * 3 + (gw < 7 ? 0 : (gw < 11 ? 1 : 2));

        // Q row straight to registers
        float qreg[32];
        const float* qp = qkv + (size_t)(bn * 49 + i) * 3072 + h * 32;
        #pragma unroll
        for (int d4 = 0; d4 < 8; ++d4) {
            float4 qv = *(const float4*)(qp + d4 * 4);
            qreg[d4 * 4 + 0] = qv.x * SCALE;
            qreg[d4 * 4 + 1] = qv.y * SCALE;
            qreg[d4 * 4 + 2] = qv.z * SCALE;
            qreg[d4 * 4 + 3] = qv.w * SCALE;
        }

        float p[49];
        float mx = -1e30f;
        #pragma unroll
        for (int j = 0; j < 49; ++j) {
            const int jh = j / 7, jw = j - jh * 7;
            float dot = 0.f;
            #pragma unroll
            for (int d = 0; d < 32; ++d) dot = fmaf(qreg[d], ks[wv][j][d], dot);
            const int ridx = (ih - jh + 6) * 13 + (iw - jw + 6);
            float val = dot + rpb[ridx * 32 + h];
            if (shifted) {
                const int gjh = wh * 7 + jh, gjw = ww_ * 7 + jw;
                const int lj = (gjh < 7 ? 0 : (gjh < 11 ? 1 : 2)) * 3 +
                               (gjw < 7 ? 0 : (gjw < 11 ? 1 : 2));
                if (li != lj) val -= 100.0f;
            }
            p[j] = val;
            mx = fmaxf(mx, val);
        }
        float denom = 0.f;
        #pragma unroll
        for (int j = 0; j < 49; ++j) {
            p[j] = expf(p[j] - mx);
            denom += p[j];
        }
        const float rd = 1.0f / denom;

        unsigned short* orow = oh + (size_t)(bn * 49 + i) * CC + h * 32;
        #pragma unroll 4
        for (int d = 0; d < 32; ++d) {
            float acc = 0.f;
            #pragma unroll
            for (int j = 0; j < 49; ++j) acc = fmaf(p[j], vs[wv][j][d], acc);
            orow[d] = f16_bits(acc * rd);
        }
    }
}

// ---------------- global-avg-pool + LayerNorm --------------------------------
__global__ __launch_bounds__(256) void pool_ln_kernel(const float* __restrict__ X,
    const float* __restrict__ g, const float* __restrict__ bta, float* __restrict__ out)
{
    int b = blockIdx.x, tid = threadIdx.x;
    int lane = tid & 63, wid = tid >> 6;
    const float* base = X + (size_t)b * 196 * CC + tid * 4;
    float a0 = 0, a1 = 0, a2 = 0, a3 = 0;
    for (int t = 0; t < 196; ++t) {
        float4 v = *(const float4*)(base + (size_t)t * CC);
        a0 += v.x; a1 += v.y; a2 += v.z; a3 += v.w;
    }
    const float inv196 = 1.0f / 196.0f;
    float p0 = a0 * inv196, p1 = a1 * inv196, p2 = a2 * inv196, p3 = a3 * inv196;
    float s = p0 + p1 + p2 + p3;
    #pragma unroll
    for (int o = 32; o; o >>= 1) s += __shfl_xor(s, o);
    __shared__ float sred[4], ssred[4];
    if (lane == 0) sred[wid] = s;
    __syncthreads();
    float mean = (sred[0] + sred[1] + sred[2] + sred[3]) * (1.0f / CC);
    float d0 = p0 - mean, d1 = p1 - mean, d2 = p2 - mean, d3 = p3 - mean;
    float ss = d0 * d0 + d1 * d1 + d2 * d2 + d3 * d3;
    #pragma unroll
    for (int o = 32; o; o >>= 1) ss += __shfl_xor(ss, o);
    if (lane == 0) ssred[wid] = ss;
    __syncthreads();
    float var = (ssred[0] + ssred[1] + ssred[2] + ssred[3]) * (1.0f / CC);
    float inv = 1.0f / sqrtf(var + 1e-5f);
    float4 gv = *(const float4*)(g + tid * 4);
    float4 bv = *(const float4*)(bta + tid * 4);
    float4 o4;
    o4.x = d0 * inv * gv.x + bv.x;
    o4.y = d1 * inv * gv.y + bv.y;
    o4.z = d2 * inv * gv.z + bv.z;
    o4.w = d3 * inv * gv.w + bv.w;
    *(float4*)(out + (size_t)b * CC + tid * 4) = o4;
}

// ---------------- head GEMM: one block per row, A row in LDS -----------------
__global__ __launch_bounds__(256) void head_rowgemm(const float* __restrict__ A,
    const float* __restrict__ W, const float* __restrict__ bias,
    float* __restrict__ out, int K, int N, int act)
{
    __shared__ float As[1024];
    int r = blockIdx.x, tid = threadIdx.x;
    for (int k = tid; k < K; k += 256) As[k] = A[(size_t)r * K + k];
    __syncthreads();
    for (int c = tid; c < N; c += 256) {
        float s0 = 0.f, s1 = 0.f;
        for (int k = 0; k < K; k += 2) {
            s0 = fmaf(As[k],     W[(size_t)k * N + c],       s0);
            s1 = fmaf(As[k + 1], W[(size_t)(k + 1) * N + c], s1);
        }
        float s = s0 + s1 + bias[c];
        out[(size_t)r * N + c] = act ? gelu_f(s) : s;
    }
}

// ---------------- launch ------------------------------------------------------
extern "C" void kernel_launch(void* const* d_in, const int* in_sizes, int n_in,
                              void* d_out, int out_size, void* d_ws, size_t ws_size,
                              hipStream_t stream) {
    const float* x = (const float*)d_in[0];
    auto P = [&](int i) { return (const float*)d_in[i]; };

    float *X, *QKV, *H0, *H1, *H2;
    unsigned short *B, *C, *Wq, *Wp, *W1, *W2;
    { void* p;
      hipGetSymbolAddress(&p, HIP_SYMBOL(g_X));   X   = (float*)p;
      hipGetSymbolAddress(&p, HIP_SYMBOL(g_QKV)); QKV = (float*)p;
      hipGetSymbolAddress(&p, HIP_SYMBOL(g_B));   B   = (unsigned short*)p;
      hipGetSymbolAddress(&p, HIP_SYMBOL(g_C));   C   = (unsigned short*)p;
      hipGetSymbolAddress(&p, HIP_SYMBOL(g_Wq));  Wq  = (unsigned short*)p;
      hipGetSymbolAddress(&p, HIP_SYMBOL(g_Wp));  Wp  = (unsigned short*)p;
      hipGetSymbolAddress(&p, HIP_SYMBOL(g_W1));  W1  = (unsigned short*)p;
      hipGetSymbolAddress(&p, HIP_SYMBOL(g_W2));  W2  = (unsigned short*)p;
      hipGetSymbolAddress(&p, HIP_SYMBOL(g_H0));  H0 = (float*)p;
      hipGetSymbolAddress(&p, HIP_SYMBOL(g_H1));  H1 = (float*)p;
      hipGetSymbolAddress(&p, HIP_SYMBOL(g_H2));  H2 = (float*)p;
    }

    hipMemcpyAsync(X, x, (size_t)NTOK * CC * sizeof(float),
                   hipMemcpyDeviceToDevice, stream);

    // weight conversion + transpose (per launch; weights are inputs)
    for (int blk = 0; blk < 2; ++blk) {
        int base = 1 + blk * 13;
        convw_kernel<<<dim3(3072/32, 1024/32), 256, 0, stream>>>(
            P(base + 2), Wq + (size_t)blk*3072*1024, 1024, 3072);
        convw_kernel<<<dim3(1024/32, 1024/32), 256, 0, stream>>>(
            P(base + 5), Wp + (size_t)blk*1024*1024, 1024, 1024);
        convw_kernel<<<dim3(4096/32, 1024/32), 256, 0, stream>>>(
            P(base + 9), W1 + (size_t)blk*4096*1024, 1024, 4096);
        convw_kernel<<<dim3(1024/32, 4096/32), 256, 0, stream>>>(
            P(base + 11), W2 + (size_t)blk*1024*4096, 4096, 1024);
    }

    for (int blk = 0; blk < 2; ++blk) {
        int base = 1 + blk * 13;
        const float *ln1g = P(base + 0), *ln1b = P(base + 1);
        const float *qkvb = P(base + 3);
        const float *rpb  = P(base + 4);
        const float *projb = P(base + 6);
        const float *ln2g = P(base + 7), *ln2b = P(base + 8);
        const float *fc1b = P(base + 10);
        const float *fc2b = P(base + 12);
        int shifted = blk;
        const unsigned short* wq = Wq + (size_t)blk*3072*1024;
        const unsigned short* wp = Wp + (size_t)blk*1024*1024;
        const unsigned short* w1 = W1 + (size_t)blk*4096*1024;
        const unsigned short* w2 = W2 + (size_t)blk*1024*4096;

        // LN1 + window partition (+shift): X -> B (fp16, window order)
        ln_kernel<<<NTOK / 4, 256, 0, stream>>>(X, ln1g, ln1b, B, shifted, 1);
        // QKV: [12544,1024] x [3072,1024]^T -> QKV fp32   (grid 2352, GC=8)
        gemm_mfma<0><<<2352, 256, 0, stream>>>(
            B, wq, qkvb, QKV, nullptr, 3072, 1024, 0, 98, 8);
        // attention -> B (fp16, window order); 4 heads/block
        attn_kernel<<<256 * 8, 256, 0, stream>>>(QKV, B, rpb, shifted);
        // proj + window-reverse (+unshift) + residual into X (grid 784, GC=8)
        gemm_mfma<2><<<784, 256, 0, stream>>>(
            B, wp, projb, X, nullptr, 1024, 1024, shifted, 98, 8);
        // LN2: X -> B
        ln_kernel<<<NTOK / 4, 256, 0, stream>>>(X, ln2g, ln2b, B, 0, 0);
        // FC1 + gelu -> C (fp16)  (grid 3136, GC=8)
        gemm_mfma<1><<<3136, 256, 0, stream>>>(
            B, w1, fc1b, nullptr, C, 4096, 1024, 0, 98, 8);
        // FC2 + residual into X   (grid 784, GC=8: A read once)
        gemm_mfma<3><<<784, 256, 0, stream>>>(
            C, w2, fc2b, X, nullptr, 1024, 4096, 0, 98, 8);
    }

    // head
    pool_ln_kernel<<<64, 256, 0, stream>>>(X, P(27), P(28), H0);
    head_rowgemm<<<64, 256, 0, stream>>>(H0, P(29), P(30), H1, 1024, 512, 1);
    head_rowgemm<<<64, 256, 0, stream>>>(H1, P(31), P(32), H2, 512, 128, 1);
    head_rowgemm<<<64, 256, 0, stream>>>(H2, P(33), P(34), (float*)d_out, 128, 2, 0);
}

// Round 10
// 1541.828 us; speedup vs baseline: 1.0896x; 1.0362x over previous
//
#include <hip/hip_runtime.h>
#include <hip/hip_bf16.h>
#include <hip/hip_fp16.h>
#include <math.h>

// ---------------- problem constants ----------------
#define BB 64
#define CC 1024
#define NH 32
#define NTOK (BB * 14 * 14)      // 12544
#define SCALE 0.17677669529663687f  // 32^-0.5

typedef __attribute__((ext_vector_type(8))) short short8;
typedef __attribute__((ext_vector_type(8))) unsigned short us8;
typedef __attribute__((ext_vector_type(4))) float f32x4;

// ---------------- static device workspace ----------------
__device__ __align__(16) float  g_X  [(size_t)NTOK * CC];          // residual (fp32)
__device__ __align__(16) unsigned short g_Qh[(size_t)NTOK * 3072];  // qkv out (fp16)
__device__ __align__(16) unsigned short g_B[(size_t)NTOK * CC];     // fp16 acts
__device__ __align__(16) unsigned short g_C[(size_t)NTOK * 4096];   // fp16 fc1 out
// transposed fp16 weights [N][K], 2 blocks each
__device__ __align__(16) unsigned short g_Wq[(size_t)2*3072*1024];
__device__ __align__(16) unsigned short g_Wp[(size_t)2*1024*1024];
__device__ __align__(16) unsigned short g_W1[(size_t)2*4096*1024];
__device__ __align__(16) unsigned short g_W2[(size_t)2*1024*4096];
__device__ __align__(16) float g_H0[64 * CC];
__device__ __align__(16) float g_H1[64 * 512];
__device__ __align__(16) float g_H2[64 * 128];

__device__ __forceinline__ float gelu_f(float x) {
    return 0.5f * x * (1.0f + erff(x * 0.70710678118654752f));
}

__device__ __forceinline__ unsigned short f16_bits(float v) {
    _Float16 hh = (_Float16)v;
    return *(unsigned short*)&hh;
}
__device__ __forceinline__ float f16_val(unsigned short u) {
    _Float16 h;
    __builtin_memcpy(&h, &u, 2);
    return (float)h;
}

// window-order row r (bn*49+t) -> row in X ([B,14,14] flattened)
__device__ __forceinline__ int win_to_xrow(int r, int shifted) {
    int bn = r / 49, t = r - bn * 49;
    int b = bn >> 2, w = bn & 3;
    int wh = w >> 1, ww_ = w & 1;
    int th = t / 7, tw = t - th * 7;
    int gh = wh * 7 + th, gw = ww_ * 7 + tw;
    if (shifted) { gh = gh + 3; if (gh >= 14) gh -= 14; gw = gw + 3; if (gw >= 14) gw -= 14; }
    return b * 196 + gh * 14 + gw;
}

__device__ __forceinline__ void gload_lds16(const void* g, void* l) {
    __builtin_amdgcn_global_load_lds(
        (const __attribute__((address_space(1))) unsigned int*)g,
        (__attribute__((address_space(3))) unsigned int*)l, 16, 0, 0);
}

// ---------------- weight convert + transpose: W[K][N] fp32 -> WT[N][K] fp16 --
__global__ __launch_bounds__(256) void convw_kernel(const float* __restrict__ W,
    unsigned short* __restrict__ Wh, int K, int N)
{
    __shared__ float t[32][33];
    int n0 = blockIdx.x * 32, k0 = blockIdx.y * 32;
    int tx = threadIdx.x & 31, ty = threadIdx.x >> 5;
    #pragma unroll
    for (int i = 0; i < 4; ++i)
        t[ty + 8 * i][tx] = W[(size_t)(k0 + ty + 8 * i) * N + n0 + tx];
    __syncthreads();
    #pragma unroll
    for (int i = 0; i < 4; ++i) {
        int n = ty + 8 * i;
        Wh[(size_t)(n0 + n) * K + k0 + tx] = f16_bits(t[tx][n]);
    }
}

// ---------------- LayerNorm -> fp16 (optional window partition+shift) --------
__global__ __launch_bounds__(256) void ln_kernel(const float* __restrict__ X,
    const float* __restrict__ g, const float* __restrict__ bta,
    unsigned short* __restrict__ outh, int shifted, int partition)
{
    int token = blockIdx.x * 4 + (threadIdx.x >> 6);
    int lane = threadIdx.x & 63;
    int xrow = partition ? win_to_xrow(token, shifted) : token;
    const float4* src = (const float4*)(X + (size_t)xrow * CC);
    float4 v[4];
    float s = 0.f;
    #pragma unroll
    for (int w = 0; w < 4; ++w) {
        v[w] = src[w * 64 + lane];
        s += v[w].x + v[w].y + v[w].z + v[w].w;
    }
    #pragma unroll
    for (int o = 32; o; o >>= 1) s += __shfl_xor(s, o);
    float mean = s * (1.0f / CC);
    float ss = 0.f;
    #pragma unroll
    for (int w = 0; w < 4; ++w) {
        float d0 = v[w].x - mean, d1 = v[w].y - mean, d2 = v[w].z - mean, d3 = v[w].w - mean;
        ss += d0 * d0 + d1 * d1 + d2 * d2 + d3 * d3;
    }
    #pragma unroll
    for (int o = 32; o; o >>= 1) ss += __shfl_xor(ss, o);
    float inv = 1.0f / sqrtf(ss * (1.0f / CC) + 1e-5f);
    #pragma unroll
    for (int w = 0; w < 4; ++w) {
        int c4 = w * 64 + lane;
        float4 gv = *(const float4*)(g + c4 * 4);
        float4 bv = *(const float4*)(bta + c4 * 4);
        ushort4 uo;
        uo.x = f16_bits((v[w].x - mean) * inv * gv.x + bv.x);
        uo.y = f16_bits((v[w].y - mean) * inv * gv.y + bv.y);
        uo.z = f16_bits((v[w].z - mean) * inv * gv.z + bv.z);
        uo.w = f16_bits((v[w].w - mean) * inv * gv.w + bv.w);
        *(ushort4*)(outh + (size_t)token * CC + c4 * 4) = uo;
    }
}

// ---------------- fp16 MFMA GEMM: C = A[M][K] * W[N][K]^T --------------------
// 128x128 tile, BK=64, 4 waves (2x2), 4x4 16x16x32 frags/wave, 32 MFMA/wave/K-tile.
// Single-buffered 32KB LDS (r8 post-mortem: explicit dbuf loses via occupancy).
// XOR swizzle slot^=row&7 on both global source and ds_read side.
// EPI: 0 fp16 store+bias, LDS-coalesced (QKV); 1 gelu -> fp16, LDS-coalesced (FC1);
//      2 residual += into X via window map (proj); 3 residual += direct (FC2)
//      (2/3 restage through LDS -> full-line float4 read-modify-write)
template<int EPI>
__global__ __launch_bounds__(256, 2) void gemm_mfma(
    const unsigned short* __restrict__ A, const unsigned short* __restrict__ W,
    const float* __restrict__ bias,
    float* __restrict__ outf, unsigned short* __restrict__ outh,
    int N, int K, int shifted, int NR, int GC)
{
    __shared__ unsigned short sm[EPI <= 1 ? 16896 : 16640];
    const int tid = threadIdx.x;
    const int wave = tid >> 6, lane = tid & 63;
    const int wr = wave >> 1, wc = wave & 1;
    // ---- grid remap: XCD chunk + col-group supertile
    const int nb = gridDim.x;
    const int wg = (blockIdx.x & 7) * (nb >> 3) + (blockIdx.x >> 3);
    const int gsz = GC * NR;
    const int grp = wg / gsz;
    const int rem = wg - grp * gsz;
    const int by = rem / GC;
    const int bx = grp * GC + (rem - by * GC);
    const int row0 = by * 128, col0 = bx * 128;
    const int rsel = lane & 15;

    f32x4 acc[4][4] = {};

    const int srow = tid >> 3, sslot = tid & 7;

    for (int k0 = 0; k0 < K; k0 += 64) {
        // ---- stage 2 tiles via global_load_lds (linear dest, swizzled source)
        #pragma unroll
        for (int i = 0; i < 8; ++i) {
            const int t = i >> 2;               // tile id 0..1 (compile-time)
            const int sub = i & 3;              // 32-row group
            const int row = sub * 32 + srow;
            const int c = sslot ^ (row & 7);    // global k-chunk for this slot
            const unsigned short* gp = (t == 0) ? A : W;
            const int rb = (t == 0) ? row0 : col0;
            gload_lds16(gp + (size_t)(rb + row) * K + k0 + c * 8,
                        &sm[t * 8192 + sub * 2048 + tid * 8]);
        }
        __syncthreads();

        // ---- per 32-K step: 8 ds_read_b128 + 16 MFMA
        #pragma unroll
        for (int kk = 0; kk < 2; ++kk) {
            const int kc8 = kk * 4 + (lane >> 4);
            short8 fa[4], fw[4];
            #pragma unroll
            for (int m = 0; m < 4; ++m) {
                int ra = wr * 64 + m * 16 + rsel;
                fa[m] = *(const short8*)&sm[ra * 64 + ((kc8 ^ (ra & 7)) * 8)];
                int rw = wc * 64 + m * 16 + rsel;
                fw[m] = *(const short8*)&sm[8192 + rw * 64 + ((kc8 ^ (rw & 7)) * 8)];
            }
            #pragma unroll
            for (int m = 0; m < 4; ++m)
                #pragma unroll
                for (int n = 0; n < 4; ++n)
                    acc[m][n] = __builtin_amdgcn_mfma_f32_16x16x32_f16(fa[m], fw[n], acc[m][n], 0, 0, 0);
        }
        __syncthreads();
    }

    // ---- epilogue: D layout col=lane&15, row=(lane>>4)*4+j
    const int jrow = lane >> 4;
    if (EPI <= 1) {
        // write tile into LDS (stride 132: conflict-free), then stream coalesced
        #pragma unroll
        for (int n = 0; n < 4; ++n) {
            int cl = wc * 64 + n * 16 + rsel;
            float bv = bias[col0 + cl];
            #pragma unroll
            for (int m = 0; m < 4; ++m)
                #pragma unroll
                for (int j = 0; j < 4; ++j) {
                    int rl = wr * 64 + m * 16 + jrow * 4 + j;
                    float v = acc[m][n][j] + bv;
                    if (EPI == 1) v = gelu_f(v);
                    sm[rl * 132 + cl] = f16_bits(v);
                }
        }
        __syncthreads();
        const int r = tid >> 1, cb = (tid & 1) * 64;
        unsigned short* dst = outh + (size_t)(row0 + r) * N + col0 + cb;
        const unsigned short* src = &sm[r * 132 + cb];
        #pragma unroll
        for (int i = 0; i < 8; ++i)
            *(us8*)(dst + i * 8) = *(const us8*)(src + i * 8);
    } else {
        // EPI 2/3: residual add, LDS restage -> full-line float4 RMW
        float* smf = (float*)sm;
        const int rr = tid >> 2;             // local row 0..63
        const int cc4 = (tid & 3) * 32;      // col offset 0/32/64/96
        #pragma unroll
        for (int half = 0; half < 2; ++half) {
            __syncthreads();
            if (wr == half) {
                #pragma unroll
                for (int n = 0; n < 4; ++n) {
                    const int cl = wc * 64 + n * 16 + rsel;
                    const float bv = bias[col0 + cl];
                    #pragma unroll
                    for (int m = 0; m < 4; ++m)
                        #pragma unroll
                        for (int j = 0; j < 4; ++j)
                            smf[(m * 16 + jrow * 4 + j) * 130 + cl] = acc[m][n][j] + bv;
                }
            }
            __syncthreads();
            const int gr = row0 + half * 64 + rr;
            const int orow = (EPI == 2) ? win_to_xrow(gr, shifted) : gr;
            float* dst = outf + (size_t)orow * CC + col0 + cc4;
            const float* srcl = &smf[rr * 130 + cc4];
            #pragma unroll
            for (int i = 0; i < 8; ++i) {
                float4 xv = *(float4*)(dst + i * 4);
                xv.x += srcl[i * 4 + 0];
                xv.y += srcl[i * 4 + 1];
                xv.z += srcl[i * 4 + 2];
                xv.w += srcl[i * 4 + 3];
                *(float4*)(dst + i * 4) = xv;
            }
        }
    }
}

// ---------------- windowed attention: 4 waves/block, one head per wave -------
// grid = 256 windows * 8 head-groups; scores in registers, K/V (fp16 in, fp32
// in LDS), all math fp32
__global__ __launch_bounds__(256) void attn_kernel(const unsigned short* __restrict__ qkv,
    unsigned short* __restrict__ oh, const float* __restrict__ rpb, int shifted)
{
    int blk = blockIdx.x;
    int bn = blk >> 3;                 // window 0..255
    int hg = blk & 7;                  // head group 0..7
    int wv = threadIdx.x >> 6;
    int lane = threadIdx.x & 63;
    int h = hg * 4 + wv;

    __shared__ float ks[4][49][32], vs[4][49][32];   // 49KB

    // each wave loads its own head's K,V
    for (int idx = lane; idx < 49 * 32; idx += 64) {
        int t = idx >> 5, d = idx & 31;
        const unsigned short* p = qkv + (size_t)(bn * 49 + t) * 3072 + h * 32 + d;
        ks[wv][t][d] = f16_val(p[1024]);
        vs[wv][t][d] = f16_val(p[2048]);
    }
    __syncthreads();

    if (lane < 49) {
        const int i = lane;
        const int ih = i / 7, iw = i - ih * 7;
        const int w = bn & 3, wh = w >> 1, ww_ = w & 1;
        const int gh = wh * 7 + ih, gw = ww_ * 7 + iw;
        const int li = (gh < 7 ? 0 : (gh < 11 ? 1 : 2)) * 3 + (gw < 7 ? 0 : (gw < 11 ? 1 : 2));

        // Q row straight to registers (fp16 -> fp32)
        float qreg[32];
        const unsigned short* qp = qkv + (size_t)(bn * 49 + i) * 3072 + h * 32;
        #pragma unroll
        for (int d8 = 0; d8 < 4; ++d8) {
            us8 qv = *(const us8*)(qp + d8 * 8);
            #pragma unroll
            for (int e = 0; e < 8; ++e) {
                unsigned short u = qv[e];
                qreg[d8 * 8 + e] = f16_val(u) * SCALE;
            }
        }

        float p[49];
        float mx = -1e30f;
        #pragma unroll
        for (int j = 0; j < 49; ++j) {
            const int jh = j / 7, jw = j - jh * 7;
            float dot = 0.f;
            #pragma unroll
            for (int d = 0; d < 32; ++d) dot = fmaf(qreg[d], ks[wv][j][d], dot);
            const int ridx = (ih - jh + 6) * 13 + (iw - jw + 6);
            float val = dot + rpb[ridx * 32 + h];
            if (shifted) {
                const int gjh = wh * 7 + jh, gjw = ww_ * 7 + jw;
                const int lj = (gjh < 7 ? 0 : (gjh < 11 ? 1 : 2)) * 3 +
                               (gjw < 7 ? 0 : (gjw < 11 ? 1 : 2));
                if (li != lj) val -= 100.0f;
            }
            p[j] = val;
            mx = fmaxf(mx, val);
        }
        float denom = 0.f;
        #pragma unroll
        for (int j = 0; j < 49; ++j) {
            p[j] = expf(p[j] - mx);
            denom += p[j];
        }
        const float rd = 1.0f / denom;

        unsigned short* orow = oh + (size_t)(bn * 49 + i) * CC + h * 32;
        #pragma unroll 4
        for (int d = 0; d < 32; ++d) {
            float acc = 0.f;
            #pragma unroll
            for (int j = 0; j < 49; ++j) acc = fmaf(p[j], vs[wv][j][d], acc);
            orow[d] = f16_bits(acc * rd);
        }
    }
}

// ---------------- global-avg-pool + LayerNorm --------------------------------
__global__ __launch_bounds__(256) void pool_ln_kernel(const float* __restrict__ X,
    const float* __restrict__ g, const float* __restrict__ bta, float* __restrict__ out)
{
    int b = blockIdx.x, tid = threadIdx.x;
    int lane = tid & 63, wid = tid >> 6;
    const float* base = X + (size_t)b * 196 * CC + tid * 4;
    float a0 = 0, a1 = 0, a2 = 0, a3 = 0;
    for (int t = 0; t < 196; ++t) {
        float4 v = *(const float4*)(base + (size_t)t * CC);
        a0 += v.x; a1 += v.y; a2 += v.z; a3 += v.w;
    }
    const float inv196 = 1.0f / 196.0f;
    float p0 = a0 * inv196, p1 = a1 * inv196, p2 = a2 * inv196, p3 = a3 * inv196;
    float s = p0 + p1 + p2 + p3;
    #pragma unroll
    for (int o = 32; o; o >>= 1) s += __shfl_xor(s, o);
    __shared__ float sred[4], ssred[4];
    if (lane == 0) sred[wid] = s;
    __syncthreads();
    float mean = (sred[0] + sred[1] + sred[2] + sred[3]) * (1.0f / CC);
    float d0 = p0 - mean, d1 = p1 - mean, d2 = p2 - mean, d3 = p3 - mean;
    float ss = d0 * d0 + d1 * d1 + d2 * d2 + d3 * d3;
    #pragma unroll
    for (int o = 32; o; o >>= 1) ss += __shfl_xor(ss, o);
    if (lane == 0) ssred[wid] = ss;
    __syncthreads();
    float var = (ssred[0] + ssred[1] + ssred[2] + ssred[3]) * (1.0f / CC);
    float inv = 1.0f / sqrtf(var + 1e-5f);
    float4 gv = *(const float4*)(g + tid * 4);
    float4 bv = *(const float4*)(bta + tid * 4);
    float4 o4;
    o4.x = d0 * inv * gv.x + bv.x;
    o4.y = d1 * inv * gv.y + bv.y;
    o4.z = d2 * inv * gv.z + bv.z;
    o4.w = d3 * inv * gv.w + bv.w;
    *(float4*)(out + (size_t)b * CC + tid * 4) = o4;
}

// ---------------- head GEMM: one block per row, A row in LDS -----------------
__global__ __launch_bounds__(256) void head_rowgemm(const float* __restrict__ A,
    const float* __restrict__ W, const float* __restrict__ bias,
    float* __restrict__ out, int K, int N, int act)
{
    __shared__ float As[1024];
    int r = blockIdx.x, tid = threadIdx.x;
    for (int k = tid; k < K; k += 256) As[k] = A[(size_t)r * K + k];
    __syncthreads();
    for (int c = tid; c < N; c += 256) {
        float s0 = 0.f, s1 = 0.f;
        for (int k = 0; k < K; k += 2) {
            s0 = fmaf(As[k],     W[(size_t)k * N + c],       s0);
            s1 = fmaf(As[k + 1], W[(size_t)(k + 1) * N + c], s1);
        }
        float s = s0 + s1 + bias[c];
        out[(size_t)r * N + c] = act ? gelu_f(s) : s;
    }
}

// ---------------- launch ------------------------------------------------------
extern "C" void kernel_launch(void* const* d_in, const int* in_sizes, int n_in,
                              void* d_out, int out_size, void* d_ws, size_t ws_size,
                              hipStream_t stream) {
    const float* x = (const float*)d_in[0];
    auto P = [&](int i) { return (const float*)d_in[i]; };

    float *X, *H0, *H1, *H2;
    unsigned short *QKVh, *B, *C, *Wq, *Wp, *W1, *W2;
    { void* p;
      hipGetSymbolAddress(&p, HIP_SYMBOL(g_X));   X    = (float*)p;
      hipGetSymbolAddress(&p, HIP_SYMBOL(g_Qh));  QKVh = (unsigned short*)p;
      hipGetSymbolAddress(&p, HIP_SYMBOL(g_B));   B    = (unsigned short*)p;
      hipGetSymbolAddress(&p, HIP_SYMBOL(g_C));   C    = (unsigned short*)p;
      hipGetSymbolAddress(&p, HIP_SYMBOL(g_Wq));  Wq   = (unsigned short*)p;
      hipGetSymbolAddress(&p, HIP_SYMBOL(g_Wp));  Wp   = (unsigned short*)p;
      hipGetSymbolAddress(&p, HIP_SYMBOL(g_W1));  W1   = (unsigned short*)p;
      hipGetSymbolAddress(&p, HIP_SYMBOL(g_W2));  W2   = (unsigned short*)p;
      hipGetSymbolAddress(&p, HIP_SYMBOL(g_H0));  H0 = (float*)p;
      hipGetSymbolAddress(&p, HIP_SYMBOL(g_H1));  H1 = (float*)p;
      hipGetSymbolAddress(&p, HIP_SYMBOL(g_H2));  H2 = (float*)p;
    }

    hipMemcpyAsync(X, x, (size_t)NTOK * CC * sizeof(float),
                   hipMemcpyDeviceToDevice, stream);

    // weight conversion + transpose (per launch; weights are inputs)
    for (int blk = 0; blk < 2; ++blk) {
        int base = 1 + blk * 13;
        convw_kernel<<<dim3(3072/32, 1024/32), 256, 0, stream>>>(
            P(base + 2), Wq + (size_t)blk*3072*1024, 1024, 3072);
        convw_kernel<<<dim3(1024/32, 1024/32), 256, 0, stream>>>(
            P(base + 5), Wp + (size_t)blk*1024*1024, 1024, 1024);
        convw_kernel<<<dim3(4096/32, 1024/32), 256, 0, stream>>>(
            P(base + 9), W1 + (size_t)blk*4096*1024, 1024, 4096);
        convw_kernel<<<dim3(1024/32, 4096/32), 256, 0, stream>>>(
            P(base + 11), W2 + (size_t)blk*1024*4096, 4096, 1024);
    }

    for (int blk = 0; blk < 2; ++blk) {
        int base = 1 + blk * 13;
        const float *ln1g = P(base + 0), *ln1b = P(base + 1);
        const float *qkvb = P(base + 3);
        const float *rpb  = P(base + 4);
        const float *projb = P(base + 6);
        const float *ln2g = P(base + 7), *ln2b = P(base + 8);
        const float *fc1b = P(base + 10);
        const float *fc2b = P(base + 12);
        int shifted = blk;
        const unsigned short* wq = Wq + (size_t)blk*3072*1024;
        const unsigned short* wp = Wp + (size_t)blk*1024*1024;
        const unsigned short* w1 = W1 + (size_t)blk*4096*1024;
        const unsigned short* w2 = W2 + (size_t)blk*1024*4096;

        // LN1 + window partition (+shift): X -> B (fp16, window order)
        ln_kernel<<<NTOK / 4, 256, 0, stream>>>(X, ln1g, ln1b, B, shifted, 1);
        // QKV: [12544,1024] x [3072,1024]^T -> QKVh fp16  (grid 2352, GC=8)
        gemm_mfma<0><<<2352, 256, 0, stream>>>(
            B, wq, qkvb, nullptr, QKVh, 3072, 1024, 0, 98, 8);
        // attention -> B (fp16, window order); 4 heads/block
        attn_kernel<<<256 * 8, 256, 0, stream>>>(QKVh, B, rpb, shifted);
        // proj + window-reverse (+unshift) + residual into X (grid 784, GC=8)
        gemm_mfma<2><<<784, 256, 0, stream>>>(
            B, wp, projb, X, nullptr, 1024, 1024, shifted, 98, 8);
        // LN2: X -> B
        ln_kernel<<<NTOK / 4, 256, 0, stream>>>(X, ln2g, ln2b, B, 0, 0);
        // FC1 + gelu -> C (fp16)  (grid 3136, GC=8)
        gemm_mfma<1><<<3136, 256, 0, stream>>>(
            B, w1, fc1b, nullptr, C, 4096, 1024, 0, 98, 8);
        // FC2 + residual into X   (grid 784, GC=8)
        gemm_mfma<3><<<784, 256, 0, stream>>>(
            C, w2, fc2b, X, nullptr, 1024, 4096, 0, 98, 8);
    }

    // head
    pool_ln_kernel<<<64, 256, 0, stream>>>(X, P(27), P(28), H0);
    head_rowgemm<<<64, 256, 0, stream>>>(H0, P(29), P(30), H1, 1024, 512, 1);
    head_rowgemm<<<64, 256, 0, stream>>>(H1, P(31), P(32), H2, 512, 128, 1);
    head_rowgemm<<<64, 256, 0, stream>>>(H2, P(33), P(34), (float*)d_out, 128, 2, 0);
}